// Round 10
// baseline (189.184 us; speedup 1.0000x reference)
//
#include <hip/hip_runtime.h>
#include <hip/hip_bf16.h>

typedef __attribute__((ext_vector_type(8))) short short8;
typedef __attribute__((ext_vector_type(4))) short bf16x4;
typedef __attribute__((ext_vector_type(4))) float floatx4;

#define T_SEQ 2048
#define NH    16
#define HD    64
#define QSCALE 0.18033688f   // 0.125 * log2(e): folded into Q at GEMM1 epilogue
#define EXP2(x) __builtin_amdgcn_exp2f(x)

// v_mfma_f32_16x16x16_bf16 (4 bf16/lane A,B; 4 f32/lane C)
#define MFMA16(a, b, c) __builtin_amdgcn_mfma_f32_16x16x16bf16_1k(a, b, c, 0, 0, 0)

__device__ __forceinline__ ushort f2bf(float f) {
    union { float f; unsigned u; } un; un.f = f;
    unsigned r = un.u + 0x7fff + ((un.u >> 16) & 1);
    return (ushort)(r >> 16);
}
__device__ __forceinline__ unsigned pkbf(float a, float b) {   // packed cvt (1 inst)
    __hip_bfloat162 t = __float22bfloat162_rn(float2{a, b});
    return *reinterpret_cast<unsigned*>(&t);
}

typedef const __attribute__((address_space(1))) unsigned int* gp1_t;
typedef __attribute__((address_space(3))) unsigned int* lp3_t;
__device__ __forceinline__ void gl_lds16(const ushort* g, ushort* l) {
    __builtin_amdgcn_global_load_lds((gp1_t)g, (lp3_t)l, 16, 0, 0);
}

// -------- fused prep: W transposes (fp32->bf16) + x convert ----------------
__global__ void prep_kernel(const float* __restrict__ Wqkv, const float* __restrict__ Wout,
                            const float* __restrict__ x, ushort* __restrict__ wt_qkv,
                            ushort* __restrict__ wt_out, ushort* __restrict__ x_bf) {
    __shared__ ushort tile[32][33];
    const int bid = blockIdx.x;
    if (bid >= 4096) {   // convert path
        size_t i = ((size_t)(bid - 4096) * 256 + threadIdx.x) * 8;
        float4 f0 = *(const float4*)(x + i);
        float4 f1 = *(const float4*)(x + i + 4);
        short8 v;
        v[0] = (short)f2bf(f0.x); v[1] = (short)f2bf(f0.y);
        v[2] = (short)f2bf(f0.z); v[3] = (short)f2bf(f0.w);
        v[4] = (short)f2bf(f1.x); v[5] = (short)f2bf(f1.y);
        v[6] = (short)f2bf(f1.z); v[7] = (short)f2bf(f1.w);
        *(short8*)(x_bf + i) = v;
        return;
    }
    const float* in; ushort* out; int R, C, gx, gy;
    if (bid < 3072) { in = Wqkv; out = wt_qkv; R = 1024; C = 3072; gx = bid % 96; gy = bid / 96; }
    else            { int t = bid - 3072; in = Wout; out = wt_out; R = 1024; C = 1024; gx = t & 31; gy = t >> 5; }
    const int tx = threadIdx.x & 31, ty = threadIdx.x >> 5;
    const int bx = gx * 32, by = gy * 32;
    #pragma unroll
    for (int i = ty; i < 32; i += 8)
        tile[i][tx] = f2bf(in[(size_t)(by + i) * C + bx + tx]);
    __syncthreads();
    #pragma unroll
    for (int i = ty; i < 32; i += 8)
        out[(size_t)(bx + i) * R + by + tx] = tile[tx][i];
}

// ---------------- GEMM: C[M][N] = A[M][K] * Bt[N][K]^T  (bf16 MFMA, fp32 acc) --
template <int EPI>
__global__ __launch_bounds__(256, 3)
void gemm_bt(const ushort* __restrict__ A, const ushort* __restrict__ Bt,
             void* __restrict__ O0, ushort* __restrict__ O1, ushort* __restrict__ O2,
             int M, int N, int K) {
    __shared__ __align__(16) ushort smem[8704];   // As[4096] | Bs[4096]; reused 64x136 for V transpose
    ushort* As = smem;
    ushort* Bs = smem + 4096;
    const int tid  = threadIdx.x;
    const int wave = tid >> 6, lane = tid & 63;
    const int quad = lane >> 4, l16 = lane & 15;
    const int wm = (wave >> 1) * 64, wn = (wave & 1) * 64;
    const int m0 = blockIdx.x * 128, n0 = blockIdx.y * 128;

    const int c0 = tid, c1 = tid + 256;
    const int row0 = c0 >> 2, row1 = c1 >> 2;
    const int g0 = (((c0 & 3) ^ ((row0 >> 1) & 3))) * 8;
    const int g1 = (((c1 & 3) ^ ((row1 >> 1) & 3))) * 8;
    const ushort* aP0 = A  + (size_t)(m0 + row0) * K + g0;
    const ushort* aP1 = A  + (size_t)(m0 + row1) * K + g1;
    const ushort* bP0 = Bt + (size_t)(n0 + row0) * K + g0;
    const ushort* bP1 = Bt + (size_t)(n0 + row1) * K + g1;

    floatx4 acc[4][4];
    #pragma unroll
    for (int i = 0; i < 4; i++)
        #pragma unroll
        for (int j = 0; j < 4; j++)
            acc[i][j] = (floatx4){0.f, 0.f, 0.f, 0.f};

    const int col_sw = (quad ^ ((l16 >> 1) & 3)) * 8;

    for (int k0 = 0; k0 < K; k0 += 32) {
        __syncthreads();
        gl_lds16(aP0 + k0, &As[c0 * 8]);
        gl_lds16(aP1 + k0, &As[c1 * 8]);
        gl_lds16(bP0 + k0, &Bs[c0 * 8]);
        gl_lds16(bP1 + k0, &Bs[c1 * 8]);
        __syncthreads();
        short8 af[4], bf[4];
        #pragma unroll
        for (int i = 0; i < 4; i++)
            af[i] = *(const short8*)(&As[(wm + i * 16 + l16) * 32 + col_sw]);
        #pragma unroll
        for (int j = 0; j < 4; j++)
            bf[j] = *(const short8*)(&Bs[(wn + j * 16 + l16) * 32 + col_sw]);
        #pragma unroll
        for (int i = 0; i < 4; i++)
            #pragma unroll
            for (int j = 0; j < 4; j++)
                acc[i][j] = __builtin_amdgcn_mfma_f32_16x16x32_bf16(af[i], bf[j], acc[i][j], 0, 0, 0);
    }

    if (EPI == 0 && n0 >= 2048) {
        // pure V block: LDS transpose -> coalesced 16B stores into vT[B,H,hd,T]
        const int b = m0 >> 11;
        const int t0 = m0 & 2047;             // token base within batch
        const int head0 = (n0 - 2048) >> 6;
        __syncthreads();                      // all waves done reading As/Bs
        #pragma unroll
        for (int nh = 0; nh < 2; nh++) {
            if ((wave & 1) == nh) {           // waves owning this 64-col half
                #pragma unroll
                for (int j = 0; j < 4; j++)
                    #pragma unroll
                    for (int i = 0; i < 4; i++) {
                        int nl = j * 16 + l16;
                        int mB = wm + i * 16 + quad * 4;
                        *(unsigned*)(&smem[nl * 136 + mB])     = pkbf(acc[i][j][0], acc[i][j][1]);
                        *(unsigned*)(&smem[nl * 136 + mB + 2]) = pkbf(acc[i][j][2], acc[i][j][3]);
                    }
            }
            __syncthreads();
            #pragma unroll
            for (int cc = 0; cc < 4; cc++) {
                int c = cc * 256 + tid;       // 1024 chunks of 8 ushorts
                int row = c >> 4, mcol = (c & 15) * 8;
                uint4 v = *(const uint4*)(&smem[row * 136 + mcol]);
                *(uint4*)(&O2[((size_t)(b * NH + head0 + nh) * HD + row) * T_SEQ + t0 + mcol]) = v;
            }
            __syncthreads();
        }
        return;
    }

    #pragma unroll
    for (int i = 0; i < 4; i++) {
        #pragma unroll
        for (int j = 0; j < 4; j++) {
            #pragma unroll
            for (int r = 0; r < 4; r++) {
                int m = m0 + wm + i * 16 + quad * 4 + r;
                int n = n0 + wn + j * 16 + l16;
                if (EPI == 0) {
                    int b = m >> 11, t = m & 2047;
                    int part = n >> 10, c = n & 1023;
                    int head = c >> 6, off = c & 63;
                    float av = acc[i][j][r];
                    if (part == 0) av *= QSCALE;     // pre-scale Q for attention
                    ushort v = f2bf(av);
                    if (part == 0) ((ushort*)O0)[(((size_t)(b * NH + head)) * T_SEQ + t) * HD + off] = v;
                    else           O1[(((size_t)(b * NH + head)) * T_SEQ + t) * HD + off] = v;
                } else {
                    ((float*)O0)[(size_t)m * N + n] = acc[i][j][r];
                }
            }
        }
    }
}

// -------- online-softmax step over one 64-key S^T tile (per-lane scalar state) --
// Wave-uniform skip of the alpha-rescale when no lane saw a new max.
__device__ __forceinline__ void softmax_step(floatx4 s[4], float& mst, float& lst,
                                             floatx4 o[4], bf16x4 pf[4]) {
    float t0 = fmaxf(fmaxf(s[0][0], s[0][1]), fmaxf(s[0][2], s[0][3]));
    float t1 = fmaxf(fmaxf(s[1][0], s[1][1]), fmaxf(s[1][2], s[1][3]));
    float t2 = fmaxf(fmaxf(s[2][0], s[2][1]), fmaxf(s[2][2], s[2][3]));
    float t3 = fmaxf(fmaxf(s[3][0], s[3][1]), fmaxf(s[3][2], s[3][3]));
    float t = fmaxf(fmaxf(t0, t1), fmaxf(t2, t3));
    t = fmaxf(t, __shfl_xor(t, 16));
    t = fmaxf(t, __shfl_xor(t, 32));
    const bool nm = t > mst;
    const float mnew = nm ? t : mst;
    float lsum = 0.f;
    #pragma unroll
    for (int j = 0; j < 4; j++) {
        float p0 = EXP2(s[j][0] - mnew);
        float p1 = EXP2(s[j][1] - mnew);
        float p2 = EXP2(s[j][2] - mnew);
        float p3 = EXP2(s[j][3] - mnew);
        lsum += (p0 + p1) + (p2 + p3);
        union { bf16x4 v; unsigned u[2]; } pu;
        pu.u[0] = pkbf(p0, p1);
        pu.u[1] = pkbf(p2, p3);
        pf[j] = pu.v;
    }
    lsum += __shfl_xor(lsum, 16);
    lsum += __shfl_xor(lsum, 32);
    if (__ballot(nm)) {          // wave-uniform branch
        float alpha = EXP2(mst - mnew);
        mst = mnew;
        lst = lst * alpha + lsum;
        #pragma unroll
        for (int db = 0; db < 4; db++)
            #pragma unroll
            for (int r = 0; r < 4; r++) o[db][r] *= alpha;
    } else {
        lst += lsum;
    }
}

// ---------------- flash attention, split-K chunks, 5 blocks/CU ---------------
// Chunk c (0..47) x bh (0..31), idx = c*32+bh, heavy chunks first:
//   c<32: qt = 31-(c>>1), half = c&1, hi = (qt+2)>>1:
//         half0: kt in [0,hi)  half1: kt in [hi,qt]  -> fp32 partial (m,l,O^T)
//   c>=32: qt = 47-c (15..0), full row kt in [0,qt] -> final bf16 output
// All chunks <= 16 iters; 1536 blocks backfill at 5/CU (LDS 5x32KB = 160KB).
__global__ __launch_bounds__(256, 5)
void attn_kernel(const ushort* __restrict__ Q, const ushort* __restrict__ Kk,
                 const ushort* __restrict__ Vt, ushort* __restrict__ Oout,
                 float* __restrict__ pm, float* __restrict__ pl, float* __restrict__ po) {
    __shared__ __align__(16) ushort KsA[8192];   // 2 x 64x64 dbuf
    __shared__ __align__(16) ushort VsA[8192];
    const int tid  = threadIdx.x;
    const int wave = tid >> 6, lane = tid & 63;
    const int quad = lane >> 4, l16 = lane & 15;
    const int idx = blockIdx.x;
    const int c = idx >> 5, bh = idx & 31;
    const int b = bh >> 4, h = bh & 15;

    int qt, kb, ke, slot = 0;
    bool partial;
    if (c < 32) {
        const int half = c & 1;
        qt = 31 - (c >> 1);
        const int hi = (qt + 2) >> 1;
        if (half == 0) { kb = 0;  ke = hi - 1; }
        else           { kb = hi; ke = qt;     }
        partial = true;
        slot = (bh * 16 + (qt - 16)) * 2 + half;
    } else {
        qt = 47 - c; kb = 0; ke = qt; partial = false;
    }

    const ushort* qp = Q  + (size_t)bh * T_SEQ * HD;
    const ushort* kp = Kk + (size_t)bh * T_SEQ * HD;
    const ushort* vp = Vt + (size_t)bh * HD * T_SEQ;

    const int q0w = qt * 64 + wave * 16;    // this wave's 16 q rows

    short8 qf[2];                           // B-operand: n=q=l16, k=d (pre-scaled)
    #pragma unroll
    for (int kbd = 0; kbd < 2; kbd++)
        qf[kbd] = *(const short8*)(qp + (size_t)(q0w + l16) * HD + kbd * 32 + quad * 8);

    floatx4 o[4];                           // O^T accum: d = db*16+quad*4+r, q = l16
    #pragma unroll
    for (int db = 0; db < 4; db++) o[db] = (floatx4){0.f, 0.f, 0.f, 0.f};
    float mst = -1e30f, lst = 0.f;

    // staging: 512 chunks of 16B per operand; thread covers c0 = tid, c1 = tid+256.
    const int c0 = tid, c1 = tid + 256;
    const int r0 = c0 >> 3, r1 = c1 >> 3;
    const int g0 = ((c0 & 7) ^ (r0 & 7)) * 8;
    const int g1 = ((c1 & 7) ^ (r1 & 7)) * 8;
    const size_t koff0 = (size_t)r0 * HD + g0,     koff1 = (size_t)r1 * HD + g1;
    const size_t voff0 = (size_t)r0 * T_SEQ + g0,  voff1 = (size_t)r1 * T_SEQ + g1;

    {   // prologue: stage tile kb into buffer 0
        const size_t kst = (size_t)kb * 64 * HD;
        const int    vst = kb * 64;
        gl_lds16(kp + kst + koff0, &KsA[c0 * 8]);
        gl_lds16(kp + kst + koff1, &KsA[c1 * 8]);
        gl_lds16(vp + vst + voff0, &VsA[c0 * 8]);
        gl_lds16(vp + vst + voff1, &VsA[c1 * 8]);
    }

    // hoisted LDS fragment addresses (ushort indices)
    const int xsw = (l16 & 7), qh = quad >> 1, ql = quad & 1;
    const int ka0 = l16 * 64 + ((quad ^ xsw) * 8);
    const int ka1 = l16 * 64 + (((4 + quad) ^ xsw) * 8);
    int va[4];
    #pragma unroll
    for (int jj = 0; jj < 4; jj++)
        va[jj] = l16 * 64 + (((2 * jj + qh) ^ xsw) * 8) + ql * 4;

    for (int kt = kb; kt <= ke; ++kt) {
        const int bo = ((kt - kb) & 1) << 12;   // ushort offset of active buffer
        __syncthreads();                        // tile-kt staging complete
        if (kt < ke) {                          // issue kt+1; lands during compute
            const size_t kn = (size_t)(kt + 1) * 64 * HD;
            const int    vn = (kt + 1) * 64;
            const int    bn = bo ^ 4096;
            gl_lds16(kp + kn + koff0, &KsA[bn + c0 * 8]);
            gl_lds16(kp + kn + koff1, &KsA[bn + c1 * 8]);
            gl_lds16(vp + vn + voff0, &VsA[bn + c0 * 8]);
            gl_lds16(vp + vn + voff1, &VsA[bn + c1 * 8]);
        }

        floatx4 s[4];
        #pragma unroll
        for (int jj = 0; jj < 4; jj++) s[jj] = (floatx4){0.f, 0.f, 0.f, 0.f};
        #pragma unroll
        for (int jj = 0; jj < 4; jj++) {
            short8 kf0 = *(const short8*)(&KsA[bo + ka0 + jj * 1024]);
            s[jj] = __builtin_amdgcn_mfma_f32_16x16x32_bf16(kf0, qf[0], s[jj], 0, 0, 0);
        }
        #pragma unroll
        for (int jj = 0; jj < 4; jj++) {
            short8 kf1 = *(const short8*)(&KsA[bo + ka1 + jj * 1024]);
            s[jj] = __builtin_amdgcn_mfma_f32_16x16x32_bf16(kf1, qf[1], s[jj], 0, 0, 0);
        }

        if (kt == qt) {   // diagonal tile (only reachable when ke == qt)
            #pragma unroll
            for (int jj = 0; jj < 4; jj++)
                #pragma unroll
                for (int rr = 0; rr < 4; rr++) {
                    int key = kt * 64 + jj * 16 + quad * 4 + rr;
                    if (key > q0w + l16) s[jj][rr] = -1e30f;
                }
        }

        bf16x4 pf[4];
        softmax_step(s, mst, lst, o, pf);

        #pragma unroll
        for (int jj = 0; jj < 4; jj++)
            #pragma unroll
            for (int db = 0; db < 4; db++) {
                bf16x4 vf = *(const bf16x4*)(&VsA[bo + va[jj] + db * 1024]);
                o[db] = MFMA16(vf, pf[jj], o[db]);
            }
    }

    if (partial) {
        const int row = wave * 16 + l16;                 // 0..63 within tile
        if (quad == 0) {
            pm[slot * 64 + row] = mst;
            pl[slot * 64 + row] = lst;
        }
        float* pob = po + (size_t)slot * 4096 + row * 64;
        #pragma unroll
        for (int db = 0; db < 4; db++)
            *(float4*)(pob + db * 16 + quad * 4) =
                (float4){o[db][0], o[db][1], o[db][2], o[db][3]};
    } else {
        const float inv = 1.0f / lst;
        const int t = q0w + l16;
        #pragma unroll
        for (int db = 0; db < 4; db++) {
            union { ushort4 w; unsigned u[2]; } ou;
            ou.u[0] = pkbf(o[db][0] * inv, o[db][1] * inv);
            ou.u[1] = pkbf(o[db][2] * inv, o[db][3] * inv);
            *(ushort4*)(Oout + (((size_t)b * T_SEQ + t) * NH + h) * HD + db * 16 + quad * 4) = ou.w;
        }
    }
}

// -------- merge the two split-K halves for qt in [16,31] ---------------------
__global__ void attn_merge(const float* __restrict__ pm, const float* __restrict__ pl,
                           const float* __restrict__ po, ushort* __restrict__ Oout) {
    const int bid = blockIdx.x;            // 512 = 32 bh x 16 qidx
    const int bh = bid >> 4, qidx = bid & 15;
    const int qt = 16 + qidx;
    const int b = bh >> 4, h = bh & 15;
    const int tid = threadIdx.x;
    const int row = tid >> 2, dq = (tid & 3) * 16;
    const int s0 = (bh * 16 + qidx) * 2, s1 = s0 + 1;

    const float m0 = pm[s0 * 64 + row], m1 = pm[s1 * 64 + row];
    const float l0 = pl[s0 * 64 + row], l1 = pl[s1 * 64 + row];
    const float m  = fmaxf(m0, m1);
    const float a0 = EXP2(m0 - m), a1 = EXP2(m1 - m);
    const float inv = 1.0f / (a0 * l0 + a1 * l1);
    const float c0 = a0 * inv, c1 = a1 * inv;

    const float* p0 = po + (size_t)s0 * 4096 + row * 64 + dq;
    const float* p1 = po + (size_t)s1 * 4096 + row * 64 + dq;
    const int t = qt * 64 + row;
    ushort* op = Oout + (((size_t)b * T_SEQ + t) * NH + h) * HD + dq;
    #pragma unroll
    for (int i = 0; i < 4; i++) {
        float4 f0 = *(const float4*)(p0 + i * 4);
        float4 f1 = *(const float4*)(p1 + i * 4);
        union { ushort4 w; unsigned u[2]; } ou;
        ou.u[0] = pkbf(c0 * f0.x + c1 * f1.x, c0 * f0.y + c1 * f1.y);
        ou.u[1] = pkbf(c0 * f0.z + c1 * f1.z, c0 * f0.w + c1 * f1.w);
        *(ushort4*)(op + i * 4) = ou.w;
    }
}

extern "C" void kernel_launch(void* const* d_in, const int* in_sizes, int n_in,
                              void* d_out, int out_size, void* d_ws, size_t ws_size,
                              hipStream_t stream) {
    const float* x    = (const float*)d_in[0];   // [2,2048,1024] fp32
    const float* Wqkv = (const float*)d_in[1];   // [1024,3072]  fp32
    const float* Wout = (const float*)d_in[2];   // [1024,1024]  fp32
    ushort* ws = (ushort*)d_ws;

    ushort* wt_qkv = ws;                               // bf16 [3072][1024]
    ushort* wt_out = wt_qkv + 3072 * 1024;             // bf16 [1024][1024]
    ushort* q_ws   = wt_out + 1024 * 1024;             // bf16 [B,H,T,hd] (pre-scaled)
    ushort* k_ws   = q_ws + 4194304;
    ushort* v_t    = k_ws + 4194304;                   // bf16 [B,H,hd,T]
    ushort* a_out  = v_t + 4194304;                    // bf16 [B,T,C]
    ushort* x_bf   = a_out + 4194304;                  // bf16 [B,T,C]
    float*  pm     = (float*)(x_bf + 4194304);         // [1024 slots][64]
    float*  pl     = pm + 65536;
    float*  po     = pl + 65536;                       // [1024 slots][64][64]

    prep_kernel<<<dim3(6144), 256, 0, stream>>>(Wqkv, Wout, x, wt_qkv, wt_out, x_bf);

    gemm_bt<0><<<dim3(32, 24), 256, 0, stream>>>(x_bf, wt_qkv, q_ws, k_ws, v_t, 4096, 3072, 1024);

    attn_kernel<<<dim3(1536), 256, 0, stream>>>(q_ws, k_ws, v_t, a_out, pm, pl, po);
    attn_merge<<<dim3(512), 256, 0, stream>>>(pm, pl, po, a_out);

    gemm_bt<1><<<dim3(32, 8), 256, 0, stream>>>(a_out, wt_out, (float*)d_out, nullptr, nullptr,
                                                4096, 1024, 1024);
}